// Round 5
// baseline (288.934 us; speedup 1.0000x reference)
//
#include <hip/hip_runtime.h>
#include <cstddef>

#define NB 64
#define NQ 64
#define NK 8192
#define ND 64
#define KPB 128          // k-tile for K1 blocks and K2 subtiles
#define SUBT 4           // K2: subtiles per block (512 k per block)

// ---------------------------------------------------------------------------
// Kernel 1: rowsum only. Round-3 QK^T register-tiled structure (thread owns
// 4q x 8k accums; Qt/Kt transposed+XOR-swizzled in LDS), softmax over q per
// key column, then rowsum[b,q] += sum_k p -- NO attn store (that 134 MB write
// moved to K2 which writes the FINAL values).
// ---------------------------------------------------------------------------
__global__ __launch_bounds__(256, 4) void k_rowsum(
    const float* __restrict__ query,
    const float* __restrict__ key,
    float* __restrict__ rowsum)
{
    __shared__ alignas(16) float Qt[64 * 64];    // [d][q swizzled] 16 KB
    __shared__ alignas(16) float Kt[32 * 128];   // [dd][k swizzled] 16 KB; M/S alias

    const int tid = threadIdx.x;
    const int b   = blockIdx.y;
    const int k0  = blockIdx.x * KPB;
    const int tq  = tid >> 4;
    const int tk  = tid & 15;

    {
        const float4* qg = reinterpret_cast<const float4*>(query + (size_t)b * NQ * ND);
#pragma unroll
        for (int i = 0; i < 4; ++i) {
            const int idx = tid + 256 * i;
            const int q   = idx >> 4;
            const int d4  = (idx & 15) * 4;
            float vv[4];
            *reinterpret_cast<float4*>(vv) = qg[idx];
#pragma unroll
            for (int j = 0; j < 4; ++j) {
                const int d = d4 + j;
                const int s = (d >> 2) & 7;
                Qt[d * 64 + ((((q >> 2) ^ s)) << 2) + (q & 3)] = vv[j];
            }
        }
    }

    float accA[4][4], accB[4][4];
#pragma unroll
    for (int qi = 0; qi < 4; ++qi)
#pragma unroll
        for (int e = 0; e < 4; ++e) { accA[qi][e] = 0.f; accB[qi][e] = 0.f; }

    const float4* kg = reinterpret_cast<const float4*>(key + ((size_t)b * NK + k0) * ND);

#pragma unroll 1
    for (int ch = 0; ch < 2; ++ch) {
        __syncthreads();
#pragma unroll
        for (int i = 0; i < 4; ++i) {
            const int idx = tid + 256 * i;
            const int k   = idx >> 3;
            const int d8  = idx & 7;
            float vv[4];
            *reinterpret_cast<float4*>(vv) = kg[k * 16 + ch * 8 + d8];
#pragma unroll
            for (int j = 0; j < 4; ++j) {
                const int dd = d8 * 4 + j;
                Kt[dd * 128 + (((k >> 2) ^ d8) << 2) + (k & 3)] = vv[j];
            }
        }
        __syncthreads();

        const int dbase = ch * 32;
#pragma unroll
        for (int d4 = 0; d4 < 8; ++d4) {
            const int s = d4;
            const float* qp = &Qt[(dbase + d4 * 4) * 64 + ((tq ^ s) << 2)];
            const float* kp = &Kt[(d4 * 4) * 128 + ((tk ^ s) << 2)];
#pragma unroll
            for (int j = 0; j < 4; ++j) {
                float qf[4], ka[4], kb[4];
                *reinterpret_cast<float4*>(qf) = *reinterpret_cast<const float4*>(qp + j * 64);
                *reinterpret_cast<float4*>(ka) = *reinterpret_cast<const float4*>(kp + j * 128);
                *reinterpret_cast<float4*>(kb) = *reinterpret_cast<const float4*>(kp + j * 128 + 64);
#pragma unroll
                for (int qi = 0; qi < 4; ++qi)
#pragma unroll
                    for (int e = 0; e < 4; ++e) {
                        accA[qi][e] = fmaf(qf[qi], ka[e], accA[qi][e]);
                        accB[qi][e] = fmaf(qf[qi], kb[e], accB[qi][e]);
                    }
            }
        }
    }

    float mA[4], mB[4];
#pragma unroll
    for (int e = 0; e < 4; ++e) {
        mA[e] = fmaxf(fmaxf(accA[0][e], accA[1][e]), fmaxf(accA[2][e], accA[3][e]));
        mB[e] = fmaxf(fmaxf(accB[0][e], accB[1][e]), fmaxf(accB[2][e], accB[3][e]));
    }
#pragma unroll
    for (int e = 0; e < 4; ++e) {
        mA[e] = fmaxf(mA[e], __shfl_xor(mA[e], 16, 64));
        mA[e] = fmaxf(mA[e], __shfl_xor(mA[e], 32, 64));
        mB[e] = fmaxf(mB[e], __shfl_xor(mB[e], 16, 64));
        mB[e] = fmaxf(mB[e], __shfl_xor(mB[e], 32, 64));
    }

    float* Mred = Kt;
    float* Sred = Kt + 512;
    const int w = tid >> 6;

    __syncthreads();
    if ((tid & 48) == 0) {
#pragma unroll
        for (int e = 0; e < 4; ++e) {
            Mred[w * 128 + 4 * tk + e]      = mA[e];
            Mred[w * 128 + 64 + 4 * tk + e] = mB[e];
        }
    }
    __syncthreads();
#pragma unroll
    for (int ww = 0; ww < 4; ++ww) {
        float ra[4], rb[4];
        *reinterpret_cast<float4*>(ra) = *reinterpret_cast<const float4*>(&Mred[ww * 128 + 4 * tk]);
        *reinterpret_cast<float4*>(rb) = *reinterpret_cast<const float4*>(&Mred[ww * 128 + 64 + 4 * tk]);
#pragma unroll
        for (int e = 0; e < 4; ++e) { mA[e] = fmaxf(mA[e], ra[e]); mB[e] = fmaxf(mB[e], rb[e]); }
    }

    float zA[4] = {0.f, 0.f, 0.f, 0.f}, zB[4] = {0.f, 0.f, 0.f, 0.f};
#pragma unroll
    for (int qi = 0; qi < 4; ++qi)
#pragma unroll
        for (int e = 0; e < 4; ++e) {
            accA[qi][e] = __expf((accA[qi][e] - mA[e]) * 0.125f); zA[e] += accA[qi][e];
            accB[qi][e] = __expf((accB[qi][e] - mB[e]) * 0.125f); zB[e] += accB[qi][e];
        }
#pragma unroll
    for (int e = 0; e < 4; ++e) {
        zA[e] += __shfl_xor(zA[e], 16, 64); zA[e] += __shfl_xor(zA[e], 32, 64);
        zB[e] += __shfl_xor(zB[e], 16, 64); zB[e] += __shfl_xor(zB[e], 32, 64);
    }
    if ((tid & 48) == 0) {
#pragma unroll
        for (int e = 0; e < 4; ++e) {
            Sred[w * 128 + 4 * tk + e]      = zA[e];
            Sred[w * 128 + 64 + 4 * tk + e] = zB[e];
        }
    }
    __syncthreads();
#pragma unroll
    for (int e = 0; e < 4; ++e) { zA[e] = 0.f; zB[e] = 0.f; }
#pragma unroll
    for (int ww = 0; ww < 4; ++ww) {
        float ra[4], rb[4];
        *reinterpret_cast<float4*>(ra) = *reinterpret_cast<const float4*>(&Sred[ww * 128 + 4 * tk]);
        *reinterpret_cast<float4*>(rb) = *reinterpret_cast<const float4*>(&Sred[ww * 128 + 64 + 4 * tk]);
#pragma unroll
        for (int e = 0; e < 4; ++e) { zA[e] += ra[e]; zB[e] += rb[e]; }
    }

    float invA[4], invB[4];
#pragma unroll
    for (int e = 0; e < 4; ++e) { invA[e] = 1.f / zA[e]; invB[e] = 1.f / zB[e]; }

#pragma unroll
    for (int qi = 0; qi < 4; ++qi) {
        float rq = 0.f;
#pragma unroll
        for (int e = 0; e < 4; ++e)
            rq += accA[qi][e] * invA[e] + accB[qi][e] * invB[e];
        rq += __shfl_xor(rq, 1, 64);
        rq += __shfl_xor(rq, 2, 64);
        rq += __shfl_xor(rq, 4, 64);
        rq += __shfl_xor(rq, 8, 64);
        if (tk == 0) atomicAdd(&rowsum[b * NQ + tq * 4 + qi], rq);
    }
}

// ---------------------------------------------------------------------------
// Kernel 2: block = (b, 512-k tile). Per 128-k subtile: RECOMPUTE QK^T +
// column softmax (round-3 structure verbatim), scale by invrow from K1,
// write FINAL attn (only attn traffic in the whole pipeline), stage p into
// LDS, PV-accumulate against LDS-staged V chunks. 16 atomicAdd/thread at end.
// LDS: Qt 16K + Kt 16K + Ps 33K + Vt 8K = 73 KB -> 2 blocks/CU.
// ---------------------------------------------------------------------------
__global__ __launch_bounds__(256, 2) void k_attn_pv(
    const float* __restrict__ query,
    const float* __restrict__ key,
    const float* __restrict__ value,
    const float* __restrict__ rowsum,
    float* __restrict__ attn,
    float* __restrict__ out)
{
    __shared__ alignas(16) float Qt[64 * 64];     // 16 KB
    __shared__ alignas(16) float Kt[32 * 128];    // 16 KB (aliased for M/S red)
    __shared__ alignas(16) float Ps[64 * 132];    // 33 KB, stride 132 (16B-aligned rows)
    __shared__ alignas(16) float Vt[32 * 64];     // 8 KB V chunk

    const int tid = threadIdx.x;
    const int b   = blockIdx.y;
    const int kb0 = blockIdx.x * (KPB * SUBT);
    const int tq  = tid >> 4;
    const int tk  = tid & 15;
    const int w   = tid >> 6;

    // stage Q transposed+swizzled (once per block)
    {
        const float4* qg = reinterpret_cast<const float4*>(query + (size_t)b * NQ * ND);
#pragma unroll
        for (int i = 0; i < 4; ++i) {
            const int idx = tid + 256 * i;
            const int q   = idx >> 4;
            const int d4  = (idx & 15) * 4;
            float vv[4];
            *reinterpret_cast<float4*>(vv) = qg[idx];
#pragma unroll
            for (int j = 0; j < 4; ++j) {
                const int d = d4 + j;
                const int s = (d >> 2) & 7;
                Qt[d * 64 + ((((q >> 2) ^ s)) << 2) + (q & 3)] = vv[j];
            }
        }
    }

    float invr[4];
#pragma unroll
    for (int qi = 0; qi < 4; ++qi)
        invr[qi] = 1.f / (rowsum[b * NQ + tq * 4 + qi] + 1e-8f);

    float pv[4][4];
#pragma unroll
    for (int qi = 0; qi < 4; ++qi)
#pragma unroll
        for (int e = 0; e < 4; ++e) pv[qi][e] = 0.f;

#pragma unroll 1
    for (int st = 0; st < SUBT; ++st) {
        const int k0 = kb0 + st * KPB;

        float accA[4][4], accB[4][4];
#pragma unroll
        for (int qi = 0; qi < 4; ++qi)
#pragma unroll
            for (int e = 0; e < 4; ++e) { accA[qi][e] = 0.f; accB[qi][e] = 0.f; }

        const float4* kg = reinterpret_cast<const float4*>(key + ((size_t)b * NK + k0) * ND);

#pragma unroll 1
        for (int ch = 0; ch < 2; ++ch) {
            __syncthreads();
#pragma unroll
            for (int i = 0; i < 4; ++i) {
                const int idx = tid + 256 * i;
                const int k   = idx >> 3;
                const int d8  = idx & 7;
                float vv[4];
                *reinterpret_cast<float4*>(vv) = kg[k * 16 + ch * 8 + d8];
#pragma unroll
                for (int j = 0; j < 4; ++j) {
                    const int dd = d8 * 4 + j;
                    Kt[dd * 128 + (((k >> 2) ^ d8) << 2) + (k & 3)] = vv[j];
                }
            }
            __syncthreads();

            const int dbase = ch * 32;
#pragma unroll
            for (int d4 = 0; d4 < 8; ++d4) {
                const int s = d4;
                const float* qp = &Qt[(dbase + d4 * 4) * 64 + ((tq ^ s) << 2)];
                const float* kp = &Kt[(d4 * 4) * 128 + ((tk ^ s) << 2)];
#pragma unroll
                for (int j = 0; j < 4; ++j) {
                    float qf[4], ka[4], kb[4];
                    *reinterpret_cast<float4*>(qf) = *reinterpret_cast<const float4*>(qp + j * 64);
                    *reinterpret_cast<float4*>(ka) = *reinterpret_cast<const float4*>(kp + j * 128);
                    *reinterpret_cast<float4*>(kb) = *reinterpret_cast<const float4*>(kp + j * 128 + 64);
#pragma unroll
                    for (int qi = 0; qi < 4; ++qi)
#pragma unroll
                        for (int e = 0; e < 4; ++e) {
                            accA[qi][e] = fmaf(qf[qi], ka[e], accA[qi][e]);
                            accB[qi][e] = fmaf(qf[qi], kb[e], accB[qi][e]);
                        }
                }
            }
        }

        // ---- column softmax over q (max + sum, cross-wave via Kt alias)
        float mA[4], mB[4];
#pragma unroll
        for (int e = 0; e < 4; ++e) {
            mA[e] = fmaxf(fmaxf(accA[0][e], accA[1][e]), fmaxf(accA[2][e], accA[3][e]));
            mB[e] = fmaxf(fmaxf(accB[0][e], accB[1][e]), fmaxf(accB[2][e], accB[3][e]));
        }
#pragma unroll
        for (int e = 0; e < 4; ++e) {
            mA[e] = fmaxf(mA[e], __shfl_xor(mA[e], 16, 64));
            mA[e] = fmaxf(mA[e], __shfl_xor(mA[e], 32, 64));
            mB[e] = fmaxf(mB[e], __shfl_xor(mB[e], 16, 64));
            mB[e] = fmaxf(mB[e], __shfl_xor(mB[e], 32, 64));
        }

        float* Mred = Kt;
        float* Sred = Kt + 512;

        __syncthreads();
        if ((tid & 48) == 0) {
#pragma unroll
            for (int e = 0; e < 4; ++e) {
                Mred[w * 128 + 4 * tk + e]      = mA[e];
                Mred[w * 128 + 64 + 4 * tk + e] = mB[e];
            }
        }
        __syncthreads();
#pragma unroll
        for (int ww = 0; ww < 4; ++ww) {
            float ra[4], rb[4];
            *reinterpret_cast<float4*>(ra) = *reinterpret_cast<const float4*>(&Mred[ww * 128 + 4 * tk]);
            *reinterpret_cast<float4*>(rb) = *reinterpret_cast<const float4*>(&Mred[ww * 128 + 64 + 4 * tk]);
#pragma unroll
            for (int e = 0; e < 4; ++e) { mA[e] = fmaxf(mA[e], ra[e]); mB[e] = fmaxf(mB[e], rb[e]); }
        }

        float zA[4] = {0.f, 0.f, 0.f, 0.f}, zB[4] = {0.f, 0.f, 0.f, 0.f};
#pragma unroll
        for (int qi = 0; qi < 4; ++qi)
#pragma unroll
            for (int e = 0; e < 4; ++e) {
                accA[qi][e] = __expf((accA[qi][e] - mA[e]) * 0.125f); zA[e] += accA[qi][e];
                accB[qi][e] = __expf((accB[qi][e] - mB[e]) * 0.125f); zB[e] += accB[qi][e];
            }
#pragma unroll
        for (int e = 0; e < 4; ++e) {
            zA[e] += __shfl_xor(zA[e], 16, 64); zA[e] += __shfl_xor(zA[e], 32, 64);
            zB[e] += __shfl_xor(zB[e], 16, 64); zB[e] += __shfl_xor(zB[e], 32, 64);
        }
        if ((tid & 48) == 0) {
#pragma unroll
            for (int e = 0; e < 4; ++e) {
                Sred[w * 128 + 4 * tk + e]      = zA[e];
                Sred[w * 128 + 64 + 4 * tk + e] = zB[e];
            }
        }
        __syncthreads();
#pragma unroll
        for (int e = 0; e < 4; ++e) { zA[e] = 0.f; zB[e] = 0.f; }
#pragma unroll
        for (int ww = 0; ww < 4; ++ww) {
            float ra[4], rb[4];
            *reinterpret_cast<float4*>(ra) = *reinterpret_cast<const float4*>(&Sred[ww * 128 + 4 * tk]);
            *reinterpret_cast<float4*>(rb) = *reinterpret_cast<const float4*>(&Sred[ww * 128 + 64 + 4 * tk]);
#pragma unroll
            for (int e = 0; e < 4; ++e) { zA[e] += ra[e]; zB[e] += rb[e]; }
        }

        float invA[4], invB[4];
#pragma unroll
        for (int e = 0; e < 4; ++e) { invA[e] = 1.f / zA[e]; invB[e] = 1.f / zB[e]; }

        // ---- final p: write attn + stage into Ps
        float* ap = attn + ((size_t)(b * NQ + tq * 4)) * NK + k0 + 4 * tk;
#pragma unroll
        for (int qi = 0; qi < 4; ++qi) {
            float pA[4], pB[4];
#pragma unroll
            for (int e = 0; e < 4; ++e) {
                pA[e] = accA[qi][e] * invA[e] * invr[qi];
                pB[e] = accB[qi][e] * invB[e] * invr[qi];
            }
            *reinterpret_cast<float4*>(ap + (size_t)qi * NK)      = *reinterpret_cast<float4*>(pA);
            *reinterpret_cast<float4*>(ap + (size_t)qi * NK + 64) = *reinterpret_cast<float4*>(pB);
            *reinterpret_cast<float4*>(&Ps[(4 * tq + qi) * 132 + 4 * tk])      = *reinterpret_cast<float4*>(pA);
            *reinterpret_cast<float4*>(&Ps[(4 * tq + qi) * 132 + 64 + 4 * tk]) = *reinterpret_cast<float4*>(pB);
        }

        // ---- PV over 4 chunks of 32 k (Vt stage + FMA)
#pragma unroll 1
        for (int vc = 0; vc < 4; ++vc) {
            __syncthreads();   // Ps visible (vc=0) / prev Vt reads done
            const float4* vg = reinterpret_cast<const float4*>(
                value + ((size_t)b * NK + k0 + vc * 32) * ND);
#pragma unroll
            for (int i = 0; i < 2; ++i) {
                const int idx = tid + 256 * i;      // 0..511
                *reinterpret_cast<float4*>(&Vt[(idx >> 4) * 64 + (idx & 15) * 4]) = vg[idx];
            }
            __syncthreads();
#pragma unroll 1
            for (int kk = 0; kk < 32; ++kk) {
                float vvv[4];
                *reinterpret_cast<float4*>(vvv) = *reinterpret_cast<const float4*>(&Vt[kk * 64 + 4 * tk]);
#pragma unroll
                for (int qi = 0; qi < 4; ++qi) {
                    const float pq = Ps[(4 * tq + qi) * 132 + vc * 32 + kk];
#pragma unroll
                    for (int e = 0; e < 4; ++e)
                        pv[qi][e] = fmaf(pq, vvv[e], pv[qi][e]);
                }
            }
        }
        __syncthreads();   // Vt/Ps done before next subtile reuses Kt/Ps
    }

#pragma unroll
    for (int qi = 0; qi < 4; ++qi) {
        float* op = out + ((size_t)(b * NQ + tq * 4 + qi)) * ND + 4 * tk;
#pragma unroll
        for (int e = 0; e < 4; ++e) atomicAdd(op + e, pv[qi][e]);
    }
}

extern "C" void kernel_launch(void* const* d_in, const int* in_sizes, int n_in,
                              void* d_out, int out_size, void* d_ws, size_t ws_size,
                              hipStream_t stream) {
    const float* query = (const float*)d_in[0];
    const float* key   = (const float*)d_in[1];
    const float* value = (const float*)d_in[2];

    float* out  = (float*)d_out;                        // [B,Q,D]
    float* attn = (float*)d_out + (size_t)NB * NQ * ND; // [B,Q,K]
    float* rowsum = (float*)d_ws;                       // [B,Q]

    hipMemsetAsync(rowsum, 0, (size_t)NB * NQ * sizeof(float), stream);
    hipMemsetAsync(out, 0, (size_t)NB * NQ * ND * sizeof(float), stream);

    dim3 g1(NK / KPB, NB);
    k_rowsum<<<g1, 256, 0, stream>>>(query, key, rowsum);

    dim3 g2(NK / (KPB * SUBT), NB);
    k_attn_pv<<<g2, 256, 0, stream>>>(query, key, value, rowsum, attn, out);
}

// Round 6
// 190.905 us; speedup vs baseline: 1.5135x; 1.5135x over previous
//
#include <hip/hip_runtime.h>
#include <cstddef>

#define NB 64
#define NQ 64
#define NK 8192
#define ND 64
#define KPB 128
#define KT 512

typedef __attribute__((ext_vector_type(8))) unsigned short ushort8_t;
typedef __attribute__((ext_vector_type(4))) unsigned short ushort4_t;

static __device__ __forceinline__ unsigned short f2bf(float f) {
    unsigned b = __float_as_uint(f);
    b += 0x7FFFu + ((b >> 16) & 1u);          // round-to-nearest-even
    return (unsigned short)(b >> 16);
}
static __device__ __forceinline__ float bf2f(unsigned short u) {
    return __uint_as_float(((unsigned)u) << 16);
}

// ---------------------------------------------------------------------------
// Kernel 1 (round-3 structure): block = (b, 128-key tile), 256 threads.
// Thread (tq,tk) owns 4q x 8k accums; Qt/Kt transposed+XOR-swizzled in LDS.
// Column softmax over q, then store UNNORMALIZED p (bf16 into ws if it fits,
// else fp32 into the attn region) + rowsum atomics (from the ROUNDED values).
// ---------------------------------------------------------------------------
template<bool BF16P>
__global__ __launch_bounds__(256, 4) void k_qk_softmax(
    const float* __restrict__ query,
    const float* __restrict__ key,
    void* __restrict__ pstore,
    float* __restrict__ rowsum)
{
    __shared__ alignas(16) float Qt[64 * 64];    // [d][q swizzled] 16 KB
    __shared__ alignas(16) float Kt[32 * 128];   // [dd][k swizzled] 16 KB; M/S alias

    const int tid = threadIdx.x;
    const int b   = blockIdx.y;
    const int k0  = blockIdx.x * KPB;
    const int tq  = tid >> 4;
    const int tk  = tid & 15;

    {
        const float4* qg = reinterpret_cast<const float4*>(query + (size_t)b * NQ * ND);
#pragma unroll
        for (int i = 0; i < 4; ++i) {
            const int idx = tid + 256 * i;
            const int q   = idx >> 4;
            const int d4  = (idx & 15) * 4;
            float vv[4];
            *reinterpret_cast<float4*>(vv) = qg[idx];
#pragma unroll
            for (int j = 0; j < 4; ++j) {
                const int d = d4 + j;
                const int s = (d >> 2) & 7;
                Qt[d * 64 + ((((q >> 2) ^ s)) << 2) + (q & 3)] = vv[j];
            }
        }
    }

    float accA[4][4], accB[4][4];
#pragma unroll
    for (int qi = 0; qi < 4; ++qi)
#pragma unroll
        for (int e = 0; e < 4; ++e) { accA[qi][e] = 0.f; accB[qi][e] = 0.f; }

    const float4* kg = reinterpret_cast<const float4*>(key + ((size_t)b * NK + k0) * ND);

#pragma unroll 1
    for (int ch = 0; ch < 2; ++ch) {
        __syncthreads();
#pragma unroll
        for (int i = 0; i < 4; ++i) {
            const int idx = tid + 256 * i;
            const int k   = idx >> 3;
            const int d8  = idx & 7;
            float vv[4];
            *reinterpret_cast<float4*>(vv) = kg[k * 16 + ch * 8 + d8];
#pragma unroll
            for (int j = 0; j < 4; ++j) {
                const int dd = d8 * 4 + j;
                Kt[dd * 128 + (((k >> 2) ^ d8) << 2) + (k & 3)] = vv[j];
            }
        }
        __syncthreads();

        const int dbase = ch * 32;
#pragma unroll
        for (int d4 = 0; d4 < 8; ++d4) {
            const int s = d4;
            const float* qp = &Qt[(dbase + d4 * 4) * 64 + ((tq ^ s) << 2)];
            const float* kp = &Kt[(d4 * 4) * 128 + ((tk ^ s) << 2)];
#pragma unroll
            for (int j = 0; j < 4; ++j) {
                float qf[4], ka[4], kb[4];
                *reinterpret_cast<float4*>(qf) = *reinterpret_cast<const float4*>(qp + j * 64);
                *reinterpret_cast<float4*>(ka) = *reinterpret_cast<const float4*>(kp + j * 128);
                *reinterpret_cast<float4*>(kb) = *reinterpret_cast<const float4*>(kp + j * 128 + 64);
#pragma unroll
                for (int qi = 0; qi < 4; ++qi)
#pragma unroll
                    for (int e = 0; e < 4; ++e) {
                        accA[qi][e] = fmaf(qf[qi], ka[e], accA[qi][e]);
                        accB[qi][e] = fmaf(qf[qi], kb[e], accB[qi][e]);
                    }
            }
        }
    }

    float mA[4], mB[4];
#pragma unroll
    for (int e = 0; e < 4; ++e) {
        mA[e] = fmaxf(fmaxf(accA[0][e], accA[1][e]), fmaxf(accA[2][e], accA[3][e]));
        mB[e] = fmaxf(fmaxf(accB[0][e], accB[1][e]), fmaxf(accB[2][e], accB[3][e]));
    }
#pragma unroll
    for (int e = 0; e < 4; ++e) {
        mA[e] = fmaxf(mA[e], __shfl_xor(mA[e], 16, 64));
        mA[e] = fmaxf(mA[e], __shfl_xor(mA[e], 32, 64));
        mB[e] = fmaxf(mB[e], __shfl_xor(mB[e], 16, 64));
        mB[e] = fmaxf(mB[e], __shfl_xor(mB[e], 32, 64));
    }

    float* Mred = Kt;
    float* Sred = Kt + 512;
    const int w = tid >> 6;

    __syncthreads();
    if ((tid & 48) == 0) {
#pragma unroll
        for (int e = 0; e < 4; ++e) {
            Mred[w * 128 + 4 * tk + e]      = mA[e];
            Mred[w * 128 + 64 + 4 * tk + e] = mB[e];
        }
    }
    __syncthreads();
#pragma unroll
    for (int ww = 0; ww < 4; ++ww) {
        float ra[4], rb[4];
        *reinterpret_cast<float4*>(ra) = *reinterpret_cast<const float4*>(&Mred[ww * 128 + 4 * tk]);
        *reinterpret_cast<float4*>(rb) = *reinterpret_cast<const float4*>(&Mred[ww * 128 + 64 + 4 * tk]);
#pragma unroll
        for (int e = 0; e < 4; ++e) { mA[e] = fmaxf(mA[e], ra[e]); mB[e] = fmaxf(mB[e], rb[e]); }
    }

    float zA[4] = {0.f, 0.f, 0.f, 0.f}, zB[4] = {0.f, 0.f, 0.f, 0.f};
#pragma unroll
    for (int qi = 0; qi < 4; ++qi)
#pragma unroll
        for (int e = 0; e < 4; ++e) {
            accA[qi][e] = __expf((accA[qi][e] - mA[e]) * 0.125f); zA[e] += accA[qi][e];
            accB[qi][e] = __expf((accB[qi][e] - mB[e]) * 0.125f); zB[e] += accB[qi][e];
        }
#pragma unroll
    for (int e = 0; e < 4; ++e) {
        zA[e] += __shfl_xor(zA[e], 16, 64); zA[e] += __shfl_xor(zA[e], 32, 64);
        zB[e] += __shfl_xor(zB[e], 16, 64); zB[e] += __shfl_xor(zB[e], 32, 64);
    }
    if ((tid & 48) == 0) {
#pragma unroll
        for (int e = 0; e < 4; ++e) {
            Sred[w * 128 + 4 * tk + e]      = zA[e];
            Sred[w * 128 + 64 + 4 * tk + e] = zB[e];
        }
    }
    __syncthreads();
#pragma unroll
    for (int e = 0; e < 4; ++e) { zA[e] = 0.f; zB[e] = 0.f; }
#pragma unroll
    for (int ww = 0; ww < 4; ++ww) {
        float ra[4], rb[4];
        *reinterpret_cast<float4*>(ra) = *reinterpret_cast<const float4*>(&Sred[ww * 128 + 4 * tk]);
        *reinterpret_cast<float4*>(rb) = *reinterpret_cast<const float4*>(&Sred[ww * 128 + 64 + 4 * tk]);
#pragma unroll
        for (int e = 0; e < 4; ++e) { zA[e] += ra[e]; zB[e] += rb[e]; }
    }

    float invA[4], invB[4];
#pragma unroll
    for (int e = 0; e < 4; ++e) { invA[e] = 1.f / zA[e]; invB[e] = 1.f / zB[e]; }

    // ---- store unnormalized p; rowsum from the ROUNDED values
#pragma unroll
    for (int qi = 0; qi < 4; ++qi) {
        float pA[4], pB[4];
#pragma unroll
        for (int e = 0; e < 4; ++e) {
            pA[e] = accA[qi][e] * invA[e];
            pB[e] = accB[qi][e] * invB[e];
        }
        float rq = 0.f;
        if (BF16P) {
            ushort4_t uA, uB;
#pragma unroll
            for (int e = 0; e < 4; ++e) {
                uA[e] = f2bf(pA[e]); uB[e] = f2bf(pB[e]);
                rq += bf2f(uA[e]) + bf2f(uB[e]);
            }
            unsigned short* pp = (unsigned short*)pstore +
                ((size_t)(b * NQ + tq * 4 + qi)) * NK + k0 + 4 * tk;
            *reinterpret_cast<ushort4_t*>(pp)      = uA;
            *reinterpret_cast<ushort4_t*>(pp + 64) = uB;
        } else {
            float* ap = (float*)pstore + ((size_t)(b * NQ + tq * 4 + qi)) * NK + k0 + 4 * tk;
            *reinterpret_cast<float4*>(ap)      = *reinterpret_cast<float4*>(pA);
            *reinterpret_cast<float4*>(ap + 64) = *reinterpret_cast<float4*>(pB);
#pragma unroll
            for (int e = 0; e < 4; ++e) rq += pA[e] + pB[e];
        }
        rq += __shfl_xor(rq, 1, 64);
        rq += __shfl_xor(rq, 2, 64);
        rq += __shfl_xor(rq, 4, 64);
        rq += __shfl_xor(rq, 8, 64);
        if (tk == 0) atomicAdd(&rowsum[b * NQ + tq * 4 + qi], rq);
    }
}

// ---------------------------------------------------------------------------
// Kernel 2: per (b, 512-key tile).
//   - load p (bf16 from ws, or fp32 in-place), scale by 1/(rowsum+eps),
//     write FINAL fp32 attn, stage into Ps
//   - out[b,q,:] += p_hat @ V via LDS tiles; float4 p-row reads in PV loop
// LDS 34 KB -> 4 blocks/CU.
// ---------------------------------------------------------------------------
template<bool BF16P>
__global__ __launch_bounds__(256, 4) void k_scale_pv(
    const float* __restrict__ value,
    const float* __restrict__ rowsum,
    const void* __restrict__ psrc,
    float* __restrict__ attn,
    float* __restrict__ out)
{
    __shared__ alignas(16) float Ps[64 * 68];
    __shared__ alignas(16) float Vs[64 * 64];
    __shared__ float invs[NQ];

    const int b  = blockIdx.y;
    const int k0 = blockIdx.x * KT;
    const int tid = threadIdx.x;

    if (tid < NQ) invs[tid] = 1.f / (rowsum[b * NQ + tid] + 1e-8f);
    __syncthreads();

    const int tq = tid >> 4;
    const int td = tid & 15;

    float acc[4][4];
#pragma unroll
    for (int qi = 0; qi < 4; ++qi)
#pragma unroll
        for (int e = 0; e < 4; ++e) acc[qi][e] = 0.f;

#pragma unroll 1
    for (int kc = 0; kc < KT; kc += 64) {
        if (BF16P) {
            const unsigned short* pb = (const unsigned short*)psrc;
#pragma unroll
            for (int i = 0; i < 2; ++i) {
                const int idx = tid + 256 * i;       // 0..511
                const int q   = idx >> 3;            // 0..63
                const int k8  = (idx & 7) * 8;       // 0..56
                const size_t gi = ((size_t)(b * NQ + q)) * NK + (size_t)(k0 + kc + k8);
                const ushort8_t u = *reinterpret_cast<const ushort8_t*>(&pb[gi]);
                const float iv = invs[q];
                float f[8];
#pragma unroll
                for (int j = 0; j < 8; ++j) f[j] = bf2f(u[j]) * iv;
                *reinterpret_cast<float4*>(&attn[gi])     = make_float4(f[0], f[1], f[2], f[3]);
                *reinterpret_cast<float4*>(&attn[gi + 4]) = make_float4(f[4], f[5], f[6], f[7]);
                *reinterpret_cast<float4*>(&Ps[q * 68 + k8])     = make_float4(f[0], f[1], f[2], f[3]);
                *reinterpret_cast<float4*>(&Ps[q * 68 + k8 + 4]) = make_float4(f[4], f[5], f[6], f[7]);
            }
        } else {
            const float* pf = (const float*)psrc;
#pragma unroll
            for (int i = 0; i < 4; ++i) {
                const int idx = tid + 256 * i;
                const int q   = idx >> 4;
                const int c4  = (idx & 15) * 4;
                const size_t gi = ((size_t)(b * NQ + q)) * NK + (size_t)(k0 + kc + c4);
                float4 p = *reinterpret_cast<const float4*>(&pf[gi]);
                const float iv = invs[q];
                p.x *= iv; p.y *= iv; p.z *= iv; p.w *= iv;
                *reinterpret_cast<float4*>(&attn[gi]) = p;
                *reinterpret_cast<float4*>(&Ps[q * 68 + c4]) = p;
            }
        }
        // stage V chunk (float4, coalesced)
#pragma unroll
        for (int i = 0; i < 4; ++i) {
            const int idx  = tid + 256 * i;
            const int krow = idx >> 4;
            const int c4   = (idx & 15) * 4;
            *reinterpret_cast<float4*>(&Vs[krow * 64 + c4]) =
                *reinterpret_cast<const float4*>(&value[((size_t)b * NK + (size_t)(k0 + kc + krow)) * ND + c4]);
        }
        __syncthreads();

        // PV: per 4-k step: 4 broadcast b128 (p rows) + 4 b128 (V rows) -> 64 FMA
#pragma unroll 4
        for (int kq = 0; kq < 16; ++kq) {
            float pqa[4][4];
#pragma unroll
            for (int qi = 0; qi < 4; ++qi)
                *reinterpret_cast<float4*>(pqa[qi]) =
                    *reinterpret_cast<const float4*>(&Ps[(4 * tq + qi) * 68 + 4 * kq]);
#pragma unroll
            for (int kk = 0; kk < 4; ++kk) {
                float vv[4];
                *reinterpret_cast<float4*>(vv) =
                    *reinterpret_cast<const float4*>(&Vs[(4 * kq + kk) * 64 + 4 * td]);
#pragma unroll
                for (int qi = 0; qi < 4; ++qi)
#pragma unroll
                    for (int e = 0; e < 4; ++e)
                        acc[qi][e] = fmaf(pqa[qi][kk], vv[e], acc[qi][e]);
            }
        }
        __syncthreads();
    }

#pragma unroll
    for (int qi = 0; qi < 4; ++qi) {
        float* op = out + ((size_t)(b * NQ + tq * 4 + qi)) * ND + 4 * td;
#pragma unroll
        for (int e = 0; e < 4; ++e) atomicAdd(op + e, acc[qi][e]);
    }
}

extern "C" void kernel_launch(void* const* d_in, const int* in_sizes, int n_in,
                              void* d_out, int out_size, void* d_ws, size_t ws_size,
                              hipStream_t stream) {
    const float* query = (const float*)d_in[0];
    const float* key   = (const float*)d_in[1];
    const float* value = (const float*)d_in[2];

    float* out  = (float*)d_out;                        // [B,Q,D]
    float* attn = (float*)d_out + (size_t)NB * NQ * ND; // [B,Q,K]
    float* rowsum = (float*)d_ws;                       // [B,Q] (16 KB)

    const size_t PB_BYTES = (size_t)NB * NQ * NK * sizeof(unsigned short); // 64 MiB
    const bool bf16p = ws_size >= 16384 + PB_BYTES;
    void* pbuf = bf16p ? (void*)((char*)d_ws + 16384) : (void*)attn;

    hipMemsetAsync(rowsum, 0, (size_t)NB * NQ * sizeof(float), stream);
    hipMemsetAsync(out, 0, (size_t)NB * NQ * ND * sizeof(float), stream);

    dim3 g1(NK / KPB, NB);
    dim3 g2(NK / KT, NB);
    if (bf16p) {
        k_qk_softmax<true><<<g1, 256, 0, stream>>>(query, key, pbuf, rowsum);
        k_scale_pv<true><<<g2, 256, 0, stream>>>(value, rowsum, pbuf, attn, out);
    } else {
        k_qk_softmax<false><<<g1, 256, 0, stream>>>(query, key, pbuf, rowsum);
        k_scale_pv<false><<<g2, 256, 0, stream>>>(value, rowsum, pbuf, attn, out);
    }
}